// Round 8
// baseline (265.772 us; speedup 1.0000x reference)
//
#include <hip/hip_runtime.h>

typedef float f32x4 __attribute__((ext_vector_type(4)));

// ---------- partner map (init via hipMemsetAsync in kernel_launch) ----------

__global__ void partner_build_kernel(const int* __restrict__ faces,
                                     int* __restrict__ partner, int n_faces) {
    int stride = gridDim.x * blockDim.x;
    for (int f = blockIdx.x * blockDim.x + threadIdx.x; f < n_faces; f += stride) {
        int a = faces[2 * f];
        int b = faces[2 * f + 1];
        partner[a] = b;
        partner[b] = a;
    }
}

__device__ __forceinline__ float vmax4(f32x4 a) {
    return fmaxf(fmaxf(a.x, a.y), fmaxf(a.z, a.w));
}
__device__ __forceinline__ float vmax8(f32x4 a, f32x4 b) {
    return fmaxf(vmax4(a), vmax4(b));
}

// One thread per 8 output channels: t = row*4 + g.  Reads its own 256 B as
// 16 contiguous dwordx4 loads (high MLP), maxes, merges the partner row
// (same-wave __shfl_xor(.,4) fast path when partner==row^1 — every face in
// this dataset; general gather fallback otherwise), stores two float4s.
__global__ void fused_pool_kernel(const float* __restrict__ feat,
                                  const int* __restrict__ partner,
                                  float* __restrict__ out, int n8) {
    int t = blockIdx.x * blockDim.x + threadIdx.x;
    if (t >= n8) return;

    int row = t >> 2;
    int g   = t & 3;                       // 8-channel group within the row
    int pr  = partner[row];

    const f32x4* p =
        reinterpret_cast<const f32x4*>(feat + (size_t)row * 256 + (size_t)g * 64);
    f32x4 v[16];
#pragma unroll
    for (int j = 0; j < 16; ++j)
        v[j] = p[j];

    float m[8];
#pragma unroll
    for (int j = 0; j < 8; ++j)
        m[j] = vmax8(v[2 * j], v[2 * j + 1]);

    // rows 2k / 2k+1 of one face are handled by lanes t and t^4 of this wave
    float pm[8];
#pragma unroll
    for (int j = 0; j < 8; ++j)
        pm[j] = __shfl_xor(m[j], 4, 64);

    if (pr >= 0) {
        if (pr == (row ^ 1)) {
#pragma unroll
            for (int j = 0; j < 8; ++j)
                m[j] = fmaxf(m[j], pm[j]);
        } else {
            const f32x4* q = reinterpret_cast<const f32x4*>(
                feat + (size_t)pr * 256 + (size_t)g * 64);
#pragma unroll
            for (int j = 0; j < 8; ++j)
                m[j] = fmaxf(m[j], vmax8(q[2 * j], q[2 * j + 1]));
        }
    }

    f32x4 o0 = {m[0], m[1], m[2], m[3]};
    f32x4 o1 = {m[4], m[5], m[6], m[7]};
    f32x4* ob = reinterpret_cast<f32x4*>(out + (size_t)t * 8);
    ob[0] = o0;
    ob[1] = o1;
}

// ---------- fallback path (no workspace needed) ----------

__global__ void base_max_kernel(const float* __restrict__ feat,
                                float* __restrict__ out, int n) {
    int stride = gridDim.x * blockDim.x;
    for (int i = blockIdx.x * blockDim.x + threadIdx.x; i < n; i += stride) {
        const f32x4* p = reinterpret_cast<const f32x4*>(feat + (size_t)i * 8);
        out[i] = vmax8(p[0], p[1]);
    }
}

__global__ void face_share_kernel(const int* __restrict__ faces,
                                  float* __restrict__ out, int n_faces) {
    int total = n_faces * 8;
    int stride = gridDim.x * blockDim.x;
    for (int t = blockIdx.x * blockDim.x + threadIdx.x; t < total; t += stride) {
        int face = t >> 3;
        int c4   = (t & 7) << 2;
        size_t f1 = (size_t)faces[2 * face];
        size_t f2 = (size_t)faces[2 * face + 1];
        float* p1 = out + f1 * 32 + c4;
        float* p2 = out + f2 * 32 + c4;
        f32x4 v1 = *reinterpret_cast<const f32x4*>(p1);
        f32x4 v2 = *reinterpret_cast<const f32x4*>(p2);
        f32x4 s;
        s.x = fmaxf(v1.x, v2.x);
        s.y = fmaxf(v1.y, v2.y);
        s.z = fmaxf(v1.z, v2.z);
        s.w = fmaxf(v1.w, v2.w);
        *reinterpret_cast<f32x4*>(p1) = s;
        *reinterpret_cast<f32x4*>(p2) = s;
    }
}

extern "C" void kernel_launch(void* const* d_in, const int* in_sizes, int n_in,
                              void* d_out, int out_size, void* d_ws, size_t ws_size,
                              hipStream_t stream) {
    const float* feat  = (const float*)d_in[0];   // (1e6, 32, 8) f32
    const int*   faces = (const int*)d_in[1];     // (400000, 2) i32
    float* out = (float*)d_out;                   // (1e6, 32) f32

    const int n_elems = out_size;                 // 32,000,000
    const int n_rows  = out_size / 32;            // 1,000,000
    const int n_faces = in_sizes[1] / 2;          // 400,000

    const int block = 256;
    const size_t partner_bytes = (size_t)n_rows * sizeof(int);

    if (ws_size >= partner_bytes && (n_elems % 512) == 0) {
        int* partner = (int*)d_ws;

        // 0xFF per byte -> every partner word == -1
        hipMemsetAsync(partner, 0xFF, partner_bytes, stream);

        int grid_f = min((n_faces + block - 1) / block, 2048);
        partner_build_kernel<<<grid_f, block, 0, stream>>>(faces, partner, n_faces);

        int n8 = n_elems / 8;                     // 4,000,000 (multiple of 64)
        int grid_m = (n8 + block - 1) / block;    // exact grid: 1 item/thread
        fused_pool_kernel<<<grid_m, block, 0, stream>>>(feat, partner, out, n8);
    } else {
        int grid_a = min((n_elems + block - 1) / block, 4096);
        base_max_kernel<<<grid_a, block, 0, stream>>>(feat, out, n_elems);

        int grid_b = min((n_faces * 8 + block - 1) / block, 4096);
        face_share_kernel<<<grid_b, block, 0, stream>>>(faces, out, n_faces);
    }
}

// Round 9
// 216.015 us; speedup vs baseline: 1.2303x; 1.2303x over previous
//
#include <hip/hip_runtime.h>

typedef float f32x4 __attribute__((ext_vector_type(4)));

// ---------- partner map (init via hipMemsetAsync in kernel_launch) ----------

__global__ void partner_build_kernel(const int* __restrict__ faces,
                                     int* __restrict__ partner, int n_faces) {
    int stride = gridDim.x * blockDim.x;
    for (int f = blockIdx.x * blockDim.x + threadIdx.x; f < n_faces; f += stride) {
        int a = faces[2 * f];
        int b = faces[2 * f + 1];
        partner[a] = b;
        partner[b] = a;
    }
}

__device__ __forceinline__ float vmax4(f32x4 a) {
    return fmaxf(fmaxf(a.x, a.y), fmaxf(a.z, a.w));
}
__device__ __forceinline__ float vmax8(f32x4 a, f32x4 b) {
    return fmaxf(vmax4(a), vmax4(b));
}

// Exactly one thread per 4 output channels: t = row*8 + c4g.  Reads its own
// 128 B as 8 dwordx4 loads, maxes, merges the partner row (same-wave shuffle
// fast path when partner==row^1 — every face in this dataset), stores float4.
// [R8 showed 256 B/thread regresses: wave count/TLP matters more than MLP.]
__global__ void fused_pool_kernel(const float* __restrict__ feat,
                                  const int* __restrict__ partner,
                                  float* __restrict__ out, int n4) {
    int t = blockIdx.x * blockDim.x + threadIdx.x;
    if (t >= n4) return;

    int row = t >> 3;
    int c4g = t & 7;
    const f32x4* p =
        reinterpret_cast<const f32x4*>(feat + (size_t)row * 256 + (size_t)c4g * 32);
    f32x4 v[8];
#pragma unroll
    for (int j = 0; j < 8; ++j)
        v[j] = p[j];

    float m[4];
#pragma unroll
    for (int j = 0; j < 4; ++j)
        m[j] = vmax8(v[2 * j], v[2 * j + 1]);

    int pr = partner[row];

    // rows 2k / 2k+1 of one face are handled by lanes t and t^8 of this wave
    float pm[4];
#pragma unroll
    for (int j = 0; j < 4; ++j)
        pm[j] = __shfl_xor(m[j], 8, 64);

    if (pr >= 0) {
        if (pr == (row ^ 1)) {
#pragma unroll
            for (int j = 0; j < 4; ++j)
                m[j] = fmaxf(m[j], pm[j]);
        } else {
            const f32x4* q = reinterpret_cast<const f32x4*>(
                feat + (size_t)pr * 256 + (size_t)c4g * 32);
#pragma unroll
            for (int j = 0; j < 4; ++j)
                m[j] = fmaxf(m[j], vmax8(q[2 * j], q[2 * j + 1]));
        }
    }

    f32x4 o = {m[0], m[1], m[2], m[3]};
    *reinterpret_cast<f32x4*>(out + (size_t)t * 4) = o;
}

// ---------- fallback path (no workspace needed) ----------

__global__ void base_max_kernel(const float* __restrict__ feat,
                                float* __restrict__ out, int n) {
    int stride = gridDim.x * blockDim.x;
    for (int i = blockIdx.x * blockDim.x + threadIdx.x; i < n; i += stride) {
        const f32x4* p = reinterpret_cast<const f32x4*>(feat + (size_t)i * 8);
        out[i] = vmax8(p[0], p[1]);
    }
}

__global__ void face_share_kernel(const int* __restrict__ faces,
                                  float* __restrict__ out, int n_faces) {
    int total = n_faces * 8;
    int stride = gridDim.x * blockDim.x;
    for (int t = blockIdx.x * blockDim.x + threadIdx.x; t < total; t += stride) {
        int face = t >> 3;
        int c4   = (t & 7) << 2;
        size_t f1 = (size_t)faces[2 * face];
        size_t f2 = (size_t)faces[2 * face + 1];
        float* p1 = out + f1 * 32 + c4;
        float* p2 = out + f2 * 32 + c4;
        f32x4 v1 = *reinterpret_cast<const f32x4*>(p1);
        f32x4 v2 = *reinterpret_cast<const f32x4*>(p2);
        f32x4 s;
        s.x = fmaxf(v1.x, v2.x);
        s.y = fmaxf(v1.y, v2.y);
        s.z = fmaxf(v1.z, v2.z);
        s.w = fmaxf(v1.w, v2.w);
        *reinterpret_cast<f32x4*>(p1) = s;
        *reinterpret_cast<f32x4*>(p2) = s;
    }
}

extern "C" void kernel_launch(void* const* d_in, const int* in_sizes, int n_in,
                              void* d_out, int out_size, void* d_ws, size_t ws_size,
                              hipStream_t stream) {
    const float* feat  = (const float*)d_in[0];   // (1e6, 32, 8) f32
    const int*   faces = (const int*)d_in[1];     // (400000, 2) i32
    float* out = (float*)d_out;                   // (1e6, 32) f32

    const int n_elems = out_size;                 // 32,000,000
    const int n_rows  = out_size / 32;            // 1,000,000
    const int n_faces = in_sizes[1] / 2;          // 400,000

    const int block = 256;
    const size_t partner_bytes = (size_t)n_rows * sizeof(int);

    if (ws_size >= partner_bytes) {
        int* partner = (int*)d_ws;

        // 0xFF per byte -> every partner word == -1
        hipMemsetAsync(partner, 0xFF, partner_bytes, stream);

        int grid_f = min((n_faces + block - 1) / block, 2048);
        partner_build_kernel<<<grid_f, block, 0, stream>>>(faces, partner, n_faces);

        int n4 = n_elems / 4;                     // 8,000,000 float4 outputs
        int grid_m = (n4 + block - 1) / block;    // exact grid: 1 item/thread
        fused_pool_kernel<<<grid_m, block, 0, stream>>>(feat, partner, out, n4);
    } else {
        int grid_a = min((n_elems + block - 1) / block, 4096);
        base_max_kernel<<<grid_a, block, 0, stream>>>(feat, out, n_elems);

        int grid_b = min((n_faces * 8 + block - 1) / block, 4096);
        face_share_kernel<<<grid_b, block, 0, stream>>>(faces, out, n_faces);
    }
}